// Round 1
// baseline (1131.880 us; speedup 1.0000x reference)
//
#include <hip/hip_runtime.h>

// Forward warp (bilinear splat), gather formulation, v3: exact binning.
//
// v2 scanned an 80x80 halo per 16x16 tile (25x redundant flow reads, the
// dominant latency source: VALUBusy 10%, HBM 11%, FETCH 480MB). v3 adds a
// binning pre-pass that reads flow ONCE (coalesced), computes each source
// pixel's exact owning tiles (1-4, from valid corner tile indices), and
// appends a 14-bit halo-relative code to a per-tile workspace list. The
// gather kernel loads its exact list (~290 entries) and keeps the proven
// LDS-atomic accumulate + non-atomic float4 writeout.
//
// Far pixels (|flow| > 30) and list overflow go to a compact far-list,
// splatted with global atomics AFTER the gather's "=" writes.

constexpr int B = 8;
constexpr int C = 16;
constexpr int H = 512;
constexpr int W = 512;
constexpr int HW = H * W;

constexpr int T    = 16;          // output tile side
constexpr int R    = 32;          // halo radius (covers |flow| <= 30)
constexpr int TX   = W / T;       // 32 tile cols
constexpr int TY   = H / T;       // 32 tile rows
constexpr int NTILE = B * TX * TY;  // 8192
constexpr int LCAP = 768;         // per-tile list capacity (expect ~290, max ~360)
constexpr int FARCAP = 1 << 16;
constexpr int ASTR = 260;         // acc channel stride: 16B-aligned, cg banks {0,16}
constexpr float FARTH = 30.0f;

// Workspace layout (bytes):
//   [0, 32768)                    int   cnt[NTILE]
//   [32768, 32772)                int   farcnt            (pad to 32896)
//   [32896, 32896+8*FARCAP)       int2  farlist[FARCAP]   (524288 B)
//   [557184, 557184+2*NTILE*LCAP) u16   list[NTILE*LCAP]  (12582912 B)
// total ~13.2 MB
constexpr size_t WS_CNT  = 0;
constexpr size_t WS_FCNT = 32768;
constexpr size_t WS_FLST = 32896;
constexpr size_t WS_LIST = WS_FLST + (size_t)FARCAP * 8;

// ---- pass 1: exact binning. One thread per source pixel. ----
__global__ __launch_bounds__(256) void fwarp_bin(
    const float* __restrict__ flow,
    int* __restrict__ cnt,
    int* __restrict__ farcnt,
    int2* __restrict__ farlist,
    unsigned short* __restrict__ list) {

  int idx = blockIdx.x * 256 + threadIdx.x;   // over B*HW
  if (idx >= B * HW) return;
  float2 f = reinterpret_cast<const float2*>(flow)[idx];
  int b  = idx >> 18;            // HW = 2^18
  int p  = idx & (HW - 1);
  int hh = p >> 9, ww = p & (W - 1);

  if (fabsf(f.x) > FARTH || fabsf(f.y) > FARTH) {
    int s = atomicAdd(farcnt, 1);
    if (s < FARCAP) farlist[s] = make_int2(idx, -1);
    return;
  }

  float x = (float)ww + f.x;
  float y = (float)hh + f.y;
  int x0 = (int)floorf(x);
  int y0 = (int)floorf(y);

  // Tiles containing a VALID corner. Matches v2's claim rule exactly:
  // tile claims iff x0 in [tx0-1, tx0+15] && y0 in [ty0-1, ty0+15], with
  // out-of-image corners dropped by the per-corner tests in the gather.
  int txA = ((unsigned)x0       < (unsigned)W) ? (x0 >> 4)       : -1;
  int txB = ((unsigned)(x0 + 1) < (unsigned)W) ? ((x0 + 1) >> 4) : -1;
  if (txB == txA) txB = -1;
  int tyA = ((unsigned)y0       < (unsigned)H) ? (y0 >> 4)       : -1;
  int tyB = ((unsigned)(y0 + 1) < (unsigned)H) ? ((y0 + 1) >> 4) : -1;
  if (tyB == tyA) tyB = -1;

  #pragma unroll
  for (int j = 0; j < 2; ++j) {
    int ty = j ? tyB : tyA;
    if (ty < 0) continue;
    #pragma unroll
    for (int i = 0; i < 2; ++i) {
      int tx = i ? txB : txA;
      if (tx < 0) continue;
      int tile = (b << 10) | (ty << 5) | tx;
      int slot = atomicAdd(&cnt[tile], 1);
      if (slot < LCAP) {
        int cy = hh - (ty * T - R);          // in [1, 78]
        int cx = ww - (tx * T - R);          // in [1, 78]
        list[(size_t)tile * LCAP + slot] = (unsigned short)((cy << 7) | cx);
      } else {
        // overflow (never expected): defer ONLY this tile's corners to far pass
        int s = atomicAdd(farcnt, 1);
        if (s < FARCAP) farlist[s] = make_int2(idx, tile);
      }
    }
  }
}

// ---- pass 2: per-tile gather. Block owns 16x16 tile x 16 channels. ----
__global__ __launch_bounds__(256, 8) void fwarp_gather(
    const float* __restrict__ im0,
    const float* __restrict__ flow,
    float* __restrict__ out,
    const int* __restrict__ cnt,
    const unsigned short* __restrict__ list) {

  __shared__ float acc[C * ASTR];   // 16*260*4 = 16640 B
  __shared__ int   queue[LCAP];     // 3072 B

  const int tcx = blockIdx.x, tcy = blockIdx.y, b = blockIdx.z;
  const int tx0 = tcx * T;
  const int ty0 = tcy * T;
  const int tid = threadIdx.x;
  const int tile = (b << 10) | (tcy << 5) | tcx;

  for (int i = tid; i < C * ASTR; i += 256) acc[i] = 0.0f;
  const int n = min(cnt[tile], LCAP);
  const unsigned short* lp = list + (size_t)tile * LCAP;
  for (int i = tid; i < n; i += 256) queue[i] = lp[i];
  __syncthreads();

  const float2* __restrict__ flowv =
      reinterpret_cast<const float2*>(flow) + (size_t)b * HW;
  const float* __restrict__ imb = im0 + (size_t)b * C * HW;
  const int hy0 = ty0 - R, wx0 = tx0 - R;

  // (entry x channel-group) work items; 4 threads per entry
  for (int k = tid; k < n * 4; k += 256) {
    int e  = k >> 2;
    int cg = (k & 3) * 4;        // channel group: 0,4,8,12
    int rel = queue[e];
    int hh = hy0 + (rel >> 7);
    int ww = wx0 + (rel & 127);
    int p  = (hh << 9) | ww;     // hh*W + ww, W = 512
    float2 f = flowv[p];         // 4 lanes same address -> broadcast, L2-hot
    float x = (float)ww + f.x;
    float y = (float)hh + f.y;
    float x0f = floorf(x), y0f = floorf(y);
    float fx = x - x0f, fy = y - y0f;
    float w00 = (1.0f - fx) * (1.0f - fy), w01 = fx * (1.0f - fy);
    float w10 = (1.0f - fx) * fy,          w11 = fx * fy;
    int lx = (int)x0f - tx0, ly = (int)y0f - ty0;
    bool cx0 = (unsigned)lx < (unsigned)T, cx1 = (unsigned)(lx + 1) < (unsigned)T;
    bool cy0 = (unsigned)ly < (unsigned)T, cy1 = (unsigned)(ly + 1) < (unsigned)T;
    int base = ly * T + lx;
    const float* sp = imb + (size_t)cg * HW + p;
    float* a = acc + cg * ASTR;
    #pragma unroll
    for (int c = 0; c < 4; ++c) {
      float v = sp[(size_t)c * HW];
      float* ac = a + c * ASTR;
      if (cx0 & cy0) atomicAdd(ac + base,         v * w00);
      if (cx1 & cy0) atomicAdd(ac + base + 1,     v * w01);
      if (cx0 & cy1) atomicAdd(ac + base + T,     v * w10);
      if (cx1 & cy1) atomicAdd(ac + base + T + 1, v * w11);
    }
  }
  __syncthreads();

  // non-atomic float4 tile writeout (exclusive ownership)
  float* ob = out + (size_t)b * C * HW + ty0 * W + tx0;
  for (int k = tid; k < C * T * T / 4; k += 256) {   // 1024 float4 stores
    int c   = k >> 6;
    int idx = k & 63;
    int r   = idx >> 2;
    int x4  = (idx & 3) * 4;
    const float* s = acc + c * ASTR + r * T + x4;
    float4 v = make_float4(s[0], s[1], s[2], s[3]);
    *reinterpret_cast<float4*>(ob + (size_t)c * HW + r * W + x4) = v;
  }
}

// ---- pass 3: far pixels + overflow entries, global-atomic splat ----
__global__ __launch_bounds__(256) void fwarp_far(
    const float* __restrict__ im0,
    const float* __restrict__ flow,
    float* __restrict__ out,
    const int* __restrict__ farcnt,
    const int2* __restrict__ farlist) {

  int nf = min(*farcnt, FARCAP);
  for (int i = blockIdx.x * 256 + threadIdx.x; i < nf; i += gridDim.x * 256) {
    int2 ent = farlist[i];
    int idx  = ent.x;
    int tile = ent.y;
    int b  = idx >> 18;
    int p  = idx & (HW - 1);
    int hh = p >> 9, ww = p & (W - 1);
    float2 f = reinterpret_cast<const float2*>(flow)[idx];
    float x = (float)ww + f.x;
    float y = (float)hh + f.y;
    float x0f = floorf(x), y0f = floorf(y);
    int x0 = (int)x0f, y0 = (int)y0f;
    float fx = x - x0f, fy = y - y0f;
    float w00 = (1.0f - fx) * (1.0f - fy), w01 = fx * (1.0f - fy);
    float w10 = (1.0f - fx) * fy,          w11 = fx * fy;

    bool vx0 = (unsigned)x0       < (unsigned)W;
    bool vx1 = (unsigned)(x0 + 1) < (unsigned)W;
    bool vy0 = (unsigned)y0       < (unsigned)H;
    bool vy1 = (unsigned)(y0 + 1) < (unsigned)H;
    if (tile >= 0) {
      // overflow entry: apply ONLY the corners inside this tile (other
      // corners were accepted by their own tiles' lists)
      int ttx = tile & 31, tty = (tile >> 5) & 31;
      int lx = x0 - ttx * T, ly = y0 - tty * T;
      vx0 &= (unsigned)lx       < (unsigned)T;
      vx1 &= (unsigned)(lx + 1) < (unsigned)T;
      vy0 &= (unsigned)ly       < (unsigned)T;
      vy1 &= (unsigned)(ly + 1) < (unsigned)T;
    }
    bool p00 = vx0 && vy0, p01 = vx1 && vy0, p10 = vx0 && vy1, p11 = vx1 && vy1;
    if (!(p00 | p01 | p10 | p11)) continue;

    int g00 = y0 * W + x0;
    const float* src = im0 + (size_t)b * C * HW + p;
    float* dst = out + (size_t)b * C * HW;
    for (int c = 0; c < C; ++c) {
      float v = src[(size_t)c * HW];
      float* o = dst + (size_t)c * HW;
      if (p00) atomicAdd(o + g00,         v * w00);
      if (p01) atomicAdd(o + g00 + 1,     v * w01);
      if (p10) atomicAdd(o + g00 + W,     v * w10);
      if (p11) atomicAdd(o + g00 + W + 1, v * w11);
    }
  }
}

extern "C" void kernel_launch(void* const* d_in, const int* in_sizes, int n_in,
                              void* d_out, int out_size, void* d_ws, size_t ws_size,
                              hipStream_t stream) {
  const float* im0  = (const float*)d_in[0];
  const float* flow = (const float*)d_in[1];
  float* out = (float*)d_out;

  char* wsb = (char*)d_ws;
  int*            cnt     = (int*)(wsb + WS_CNT);
  int*            farcnt  = (int*)(wsb + WS_FCNT);
  int2*           farlist = (int2*)(wsb + WS_FLST);
  unsigned short* list    = (unsigned short*)(wsb + WS_LIST);

  // zero counters (graph-capture-safe)
  hipMemsetAsync(wsb, 0, WS_FLST, stream);

  fwarp_bin<<<(B * HW + 255) / 256, 256, 0, stream>>>(flow, cnt, farcnt, farlist, list);

  dim3 grid(TX, TY, B);   // 32 x 32 x 8 = 8192 blocks
  fwarp_gather<<<grid, 256, 0, stream>>>(im0, flow, out, cnt, list);

  fwarp_far<<<64, 256, 0, stream>>>(im0, flow, out, farcnt, farlist);
}

// Round 2
// 542.153 us; speedup vs baseline: 2.0878x; 2.0878x over previous
//
#include <hip/hip_runtime.h>

// Forward warp (bilinear splat), v4: atomic-free gather.
//
// R1 post-mortem: removing the 25x halo scan (v2->v3) barely moved the gather
// (717->689us) while all pipes read idle -> the shared cost is the 134M LDS
// atomicAdd lane-ops (~3.1 cyc/lane-op accounts for the full 689us). The bin
// pass's ~400us similarly tracks its 2.5M device-scope global atomics.
// v4 removes both:
//  - gather: destination-major. In-LDS CSR bins entries by (x0,y0) cell
//    (17x17); each thread owns one output pixel x 16 channels in REGISTERS,
//    walks 4 cell lists, FMAs. No accumulation atomics, no LDS acc tile.
//  - im0 transposed to channels-last imT[b][p][c] (workspace): a contributor's
//    16 channels = one 64B line (4x dwordx4) instead of 16 scattered lines.
//  - bin: wave-aggregated atomics (ballot/shfl leader election) -> one
//    global atomicAdd per (wave x distinct tile); coalesced slot writes.

constexpr int B = 8;
constexpr int C = 16;
constexpr int H = 512;
constexpr int W = 512;
constexpr int HW = H * W;

constexpr int T    = 16;            // output tile side
constexpr int R    = 32;            // halo radius (covers |flow| <= 30)
constexpr int TX   = W / T;         // 32
constexpr int TY   = H / T;         // 32
constexpr int NTILE = B * TX * TY;  // 8192
constexpr int LCAP = 768;           // per-tile list cap (expect ~290, max ~360)
constexpr int FARCAP = 1 << 16;
constexpr int NCELL = 289;          // 17x17 cells; cell 289 = trash
constexpr float FARTH = 30.0f;

// Workspace layout (bytes):
//   [0, 32768)        int  cnt[NTILE]
//   [32768, 32772)    int  farcnt                       (pad to 32896)
//   [32896, +8*FARCAP) int2 farlist[FARCAP]
//   [WS_LIST, +2*NTILE*LCAP) u16 list
//   [WS_IMT,  +B*HW*C*4)     float imT[b][p][c]   (if ws_size permits)
constexpr size_t WS_CNT  = 0;
constexpr size_t WS_FCNT = 32768;
constexpr size_t WS_FLST = 32896;
constexpr size_t WS_LIST = WS_FLST + (size_t)FARCAP * 8;
constexpr size_t WS_IMT  = (WS_LIST + (size_t)NTILE * LCAP * 2 + 255) & ~(size_t)255;
constexpr size_t IMT_BYTES = (size_t)B * HW * C * 4;

// ---- pass 0: transpose im0 [B,C,H,W] -> imT [B,HW,C] (channels-last) ----
__global__ __launch_bounds__(256) void fwarp_tr(
    const float* __restrict__ im0, float* __restrict__ imT) {
  __shared__ float t[256 * 17];               // +17 stride: conflict-free
  int blk = blockIdx.x;                       // 8192 = B * (HW/256)
  int b   = blk >> 10;
  int p0  = (blk & 1023) * 256;
  const float* src = im0 + (size_t)b * C * HW + p0;
  int tid = threadIdx.x;
  #pragma unroll
  for (int c = 0; c < C; ++c)
    t[tid * 17 + c] = src[(size_t)c * HW + tid];   // coalesced global read
  __syncthreads();
  float4* dst = reinterpret_cast<float4*>(imT + ((size_t)b * HW + p0) * C);
  #pragma unroll
  for (int i = 0; i < 4; ++i) {
    int k = i * 256 + tid;                    // 1024 float4 per block
    int p = k >> 2, c4 = (k & 3) * 4;
    const float* tp = &t[p * 17 + c4];
    dst[k] = make_float4(tp[0], tp[1], tp[2], tp[3]);  // coalesced write
  }
}

// ---- pass 1: exact binning with wave-aggregated atomics ----
__global__ __launch_bounds__(256) void fwarp_bin(
    const float* __restrict__ flow,
    int* __restrict__ cnt,
    int* __restrict__ farcnt,
    int2* __restrict__ farlist,
    unsigned short* __restrict__ list) {

  int idx = blockIdx.x * 256 + threadIdx.x;   // over B*HW
  if (idx >= B * HW) return;
  int lane = threadIdx.x & 63;
  float2 f = reinterpret_cast<const float2*>(flow)[idx];
  int b  = idx >> 18;
  int p  = idx & (HW - 1);
  int hh = p >> 9, ww = p & (W - 1);

  if (fabsf(f.x) > FARTH || fabsf(f.y) > FARTH) {
    // aggregate the rare far pushes too
    unsigned long long m = __ballot(true);
    int ldr = __ffsll((long long)m) - 1;
    int base = 0;
    if (lane == ldr) base = atomicAdd(farcnt, (int)__popcll(m));
    base = __shfl(base, ldr);
    int s = base + (int)__popcll(m & ((1ull << lane) - 1));
    if (s < FARCAP) farlist[s] = make_int2(idx, -1);
    return;
  }

  float x = (float)ww + f.x;
  float y = (float)hh + f.y;
  int x0 = (int)floorf(x);
  int y0 = (int)floorf(y);

  int txA = ((unsigned)x0       < (unsigned)W) ? (x0 >> 4)       : -1;
  int txB = ((unsigned)(x0 + 1) < (unsigned)W) ? ((x0 + 1) >> 4) : -1;
  if (txB == txA) txB = -1;
  int tyA = ((unsigned)y0       < (unsigned)H) ? (y0 >> 4)       : -1;
  int tyB = ((unsigned)(y0 + 1) < (unsigned)H) ? ((y0 + 1) >> 4) : -1;
  if (tyB == tyA) tyB = -1;

  int clt[4];
  clt[0] = (tyA >= 0 && txA >= 0) ? ((b << 10) | (tyA << 5) | txA) : -1;
  clt[1] = (tyA >= 0 && txB >= 0) ? ((b << 10) | (tyA << 5) | txB) : -1;
  clt[2] = (tyB >= 0 && txA >= 0) ? ((b << 10) | (tyB << 5) | txA) : -1;
  clt[3] = (tyB >= 0 && txB >= 0) ? ((b << 10) | (tyB << 5) | txB) : -1;

  #pragma unroll
  for (int r = 0; r < 4; ++r) {
    int t = clt[r];
    bool want = (t >= 0);
    unsigned long long alive = __ballot(want);
    while (alive) {                           // uniform: ballot result
      int src = __ffsll((long long)alive) - 1;
      int t0  = __shfl(t, src);
      unsigned long long grp = __ballot(want && t == t0);
      int base = 0;
      if (lane == src) base = atomicAdd(&cnt[t0], (int)__popcll(grp));
      base = __shfl(base, src);
      if (want && t == t0) {
        int slot = base + (int)__popcll(grp & ((1ull << lane) - 1));
        int tty = (t0 >> 5) & 31, ttx = t0 & 31;
        int cy = hh - (tty * T - R);          // in [1,78]
        int cx = ww - (ttx * T - R);
        if (slot < LCAP) {
          list[(size_t)t0 * LCAP + slot] = (unsigned short)((cy << 7) | cx);
        } else {
          int s2 = atomicAdd(farcnt, 1);      // never expected
          if (s2 < FARCAP) farlist[s2] = make_int2(idx, t0);
        }
        want = false;
      }
      alive &= ~grp;
    }
  }
}

// ---- pass 2: destination-major gather, register accumulation ----
// CL=true: channels-last imT; CL=false: fallback reads im0 directly.
template <bool CL>
__global__ __launch_bounds__(256, 8) void fwarp_gather(
    const float* __restrict__ im0,
    const float* __restrict__ imT,
    const float* __restrict__ flow,
    float* __restrict__ out,
    const int* __restrict__ cnt,
    const unsigned short* __restrict__ list) {

  __shared__ int            s_cnt[320];     // cell counts, then fill cursors
  __shared__ int            s_tmp[320];     // per-segment exclusive sums
  __shared__ int            s_seg[32];
  __shared__ int            s_start[292];   // exclusive starts [0..290]
  __shared__ int            s_p[LCAP];
  __shared__ float2         s_f[LCAP];
  __shared__ unsigned short s_cellid[LCAP];
  __shared__ unsigned short s_ord[LCAP];

  const int tcx = blockIdx.x, tcy = blockIdx.y, b = blockIdx.z;
  const int tx0 = tcx * T, ty0 = tcy * T;
  const int tid = threadIdx.x;
  const int tile = (b << 10) | (tcy << 5) | tcx;
  const int hy0 = ty0 - R, wx0 = tx0 - R;

  for (int i = tid; i < 320; i += 256) s_cnt[i] = 0;
  __syncthreads();

  const float2* __restrict__ flowv =
      reinterpret_cast<const float2*>(flow) + (size_t)b * HW;
  const int n = min(cnt[tile], LCAP);
  const unsigned short* lp = list + (size_t)tile * LCAP;

  // 2a: decode entries, compute cell + fractional offsets, count per cell
  for (int i = tid; i < n; i += 256) {
    int rc = lp[i];
    int hh = hy0 + (rc >> 7);
    int ww = wx0 + (rc & 127);
    int p  = (hh << 9) | ww;
    float2 f = flowv[p];
    float x = (float)ww + f.x, y = (float)hh + f.y;
    float x0f = floorf(x), y0f = floorf(y);
    int cx = (int)x0f - tx0 + 1;
    int cy = (int)y0f - ty0 + 1;
    int cell = ((unsigned)cx <= 16u && (unsigned)cy <= 16u) ? cy * 17 + cx
                                                           : NCELL;  // trash
    s_p[i] = p;
    s_f[i] = make_float2(x - x0f, y - y0f);
    s_cellid[i] = (unsigned short)cell;
    atomicAdd(&s_cnt[cell], 1);
  }
  __syncthreads();

  // exclusive prefix sum over 291 counts (trash included), segmented
  if (tid < 32) {
    int sum = 0;
    #pragma unroll
    for (int j = 0; j < 10; ++j) {
      int ix = tid * 10 + j;
      s_tmp[ix] = sum;
      sum += s_cnt[ix];
    }
    s_seg[tid] = sum;
  }
  __syncthreads();
  if (tid == 0) {
    int run = 0;
    for (int t = 0; t < 32; ++t) { int v = s_seg[t]; s_seg[t] = run; run += v; }
  }
  __syncthreads();
  for (int i = tid; i <= 290; i += 256) s_start[i] = s_tmp[i] + s_seg[i / 10];
  for (int i = tid; i < 320; i += 256) s_cnt[i] = 0;   // -> fill cursors
  __syncthreads();

  // 2b: scatter entry ids into CSR order
  for (int i = tid; i < n; i += 256) {
    int cell = s_cellid[i];
    int pos = s_start[cell] + atomicAdd(&s_cnt[cell], 1);
    s_ord[pos] = (unsigned short)i;
  }
  __syncthreads();

  // 2c: one thread per output pixel, 16-channel register accumulation
  float a[16];
  #pragma unroll
  for (int c = 0; c < 16; ++c) a[c] = 0.0f;
  const int lx = tid & 15, ly = tid >> 4;

  #pragma unroll
  for (int k = 0; k < 4; ++k) {
    int cx = lx + 1 - (k & 1);         // cell holding corner k's sources
    int cy = ly + 1 - (k >> 1);
    int cell = cy * 17 + cx;
    int s = s_start[cell], e = s_start[cell + 1];
    for (int j = s; j < e; ++j) {
      int id = s_ord[j];
      float2 f = s_f[id];
      float wgt = ((k & 1) ? f.x : 1.0f - f.x) * ((k >> 1) ? f.y : 1.0f - f.y);
      int p = s_p[id];
      if (CL) {
        const float4* v4 =
            reinterpret_cast<const float4*>(imT) + ((size_t)b * HW + p) * 4;
        float4 q0 = v4[0], q1 = v4[1], q2 = v4[2], q3 = v4[3];
        a[0]  += wgt * q0.x; a[1]  += wgt * q0.y;
        a[2]  += wgt * q0.z; a[3]  += wgt * q0.w;
        a[4]  += wgt * q1.x; a[5]  += wgt * q1.y;
        a[6]  += wgt * q1.z; a[7]  += wgt * q1.w;
        a[8]  += wgt * q2.x; a[9]  += wgt * q2.y;
        a[10] += wgt * q2.z; a[11] += wgt * q2.w;
        a[12] += wgt * q3.x; a[13] += wgt * q3.y;
        a[14] += wgt * q3.z; a[15] += wgt * q3.w;
      } else {
        const float* sp = im0 + (size_t)b * C * HW + p;
        #pragma unroll
        for (int c = 0; c < 16; ++c) a[c] += wgt * sp[(size_t)c * HW];
      }
    }
  }

  // direct register->global writeout (exclusive ownership, coalesced per c)
  float* ob = out + (size_t)b * C * HW + (size_t)(ty0 + ly) * W + (tx0 + lx);
  #pragma unroll
  for (int c = 0; c < 16; ++c) ob[(size_t)c * HW] = a[c];
}

// ---- pass 3: far pixels + overflow entries, global-atomic splat ----
__global__ __launch_bounds__(256) void fwarp_far(
    const float* __restrict__ im0,
    const float* __restrict__ flow,
    float* __restrict__ out,
    const int* __restrict__ farcnt,
    const int2* __restrict__ farlist) {

  int nf = min(*farcnt, FARCAP);
  for (int i = blockIdx.x * 256 + threadIdx.x; i < nf; i += gridDim.x * 256) {
    int2 ent = farlist[i];
    int idx  = ent.x;
    int tile = ent.y;
    int b  = idx >> 18;
    int p  = idx & (HW - 1);
    int hh = p >> 9, ww = p & (W - 1);
    float2 f = reinterpret_cast<const float2*>(flow)[idx];
    float x = (float)ww + f.x;
    float y = (float)hh + f.y;
    float x0f = floorf(x), y0f = floorf(y);
    int x0 = (int)x0f, y0 = (int)y0f;
    float fx = x - x0f, fy = y - y0f;
    float w00 = (1.0f - fx) * (1.0f - fy), w01 = fx * (1.0f - fy);
    float w10 = (1.0f - fx) * fy,          w11 = fx * fy;

    bool vx0 = (unsigned)x0       < (unsigned)W;
    bool vx1 = (unsigned)(x0 + 1) < (unsigned)W;
    bool vy0 = (unsigned)y0       < (unsigned)H;
    bool vy1 = (unsigned)(y0 + 1) < (unsigned)H;
    if (tile >= 0) {
      // overflow entry: apply ONLY corners landing in this tile's pixels
      int ttx = tile & 31, tty = (tile >> 5) & 31;
      int lx = x0 - ttx * T, ly = y0 - tty * T;
      vx0 &= (unsigned)lx       < (unsigned)T;
      vx1 &= (unsigned)(lx + 1) < (unsigned)T;
      vy0 &= (unsigned)ly       < (unsigned)T;
      vy1 &= (unsigned)(ly + 1) < (unsigned)T;
    }
    bool p00 = vx0 && vy0, p01 = vx1 && vy0, p10 = vx0 && vy1, p11 = vx1 && vy1;
    if (!(p00 | p01 | p10 | p11)) continue;

    int g00 = y0 * W + x0;
    const float* src = im0 + (size_t)b * C * HW + p;
    float* dst = out + (size_t)b * C * HW;
    for (int c = 0; c < C; ++c) {
      float v = src[(size_t)c * HW];
      float* o = dst + (size_t)c * HW;
      if (p00) atomicAdd(o + g00,         v * w00);
      if (p01) atomicAdd(o + g00 + 1,     v * w01);
      if (p10) atomicAdd(o + g00 + W,     v * w10);
      if (p11) atomicAdd(o + g00 + W + 1, v * w11);
    }
  }
}

extern "C" void kernel_launch(void* const* d_in, const int* in_sizes, int n_in,
                              void* d_out, int out_size, void* d_ws, size_t ws_size,
                              hipStream_t stream) {
  const float* im0  = (const float*)d_in[0];
  const float* flow = (const float*)d_in[1];
  float* out = (float*)d_out;

  char* wsb = (char*)d_ws;
  int*            cnt     = (int*)(wsb + WS_CNT);
  int*            farcnt  = (int*)(wsb + WS_FCNT);
  int2*           farlist = (int2*)(wsb + WS_FLST);
  unsigned short* list    = (unsigned short*)(wsb + WS_LIST);
  float*          imT     = (float*)(wsb + WS_IMT);

  const bool useT = ws_size >= WS_IMT + IMT_BYTES;

  hipMemsetAsync(wsb, 0, WS_FLST, stream);   // cnt + farcnt

  if (useT) fwarp_tr<<<8192, 256, 0, stream>>>(im0, imT);

  fwarp_bin<<<(B * HW + 255) / 256, 256, 0, stream>>>(
      flow, cnt, farcnt, farlist, list);

  dim3 grid(TX, TY, B);
  if (useT)
    fwarp_gather<true><<<grid, 256, 0, stream>>>(im0, imT, flow, out, cnt, list);
  else
    fwarp_gather<false><<<grid, 256, 0, stream>>>(im0, imT, flow, out, cnt, list);

  fwarp_far<<<64, 256, 0, stream>>>(im0, flow, out, farcnt, farlist);
}

// Round 3
// 470.860 us; speedup vs baseline: 2.4039x; 1.1514x over previous
//
#include <hip/hip_runtime.h>

// Forward warp (bilinear splat), v5.
//
// R2 post-mortem: atomic-free gather (v4) hit 148us; remaining ~390us is the
// helper passes (tr ~ + bin ~ + far + gaps). Gather's own limiter: phase 2c
// re-loads each contributor's 64B channel vector from global once PER VISITING
// PIXEL (4x), every lane a distinct cache line -> vector-L1 line-transaction
// serialization (~40% of gather cycles).
// v5:
//  - gather: stage each entry's 16 channels ONCE into LDS (coalesced, 4
//    lanes/line), visits read LDS. vch[400][16] = 25.6KB, total LDS 40.3KB
//    -> 4 blocks/CU.
//  - prep: fuse the channels-last transpose and the binning pass. Bin's
//    ballot-aggregated atomics hide under the 256MB streaming transpose.
//  - far pass unchanged (rare |flow|>30 + overflow, global atomics).

constexpr int B = 8;
constexpr int C = 16;
constexpr int H = 512;
constexpr int W = 512;
constexpr int HW = H * W;

constexpr int T    = 16;            // output tile side
constexpr int R    = 32;            // halo radius (covers |flow| <= 30)
constexpr int TX   = W / T;         // 32
constexpr int TY   = H / T;         // 32
constexpr int NTILE = B * TX * TY;  // 8192
constexpr int LCAP = 768;           // per-tile list cap (expect ~290, max ~380)
constexpr int VSTAGE = 400;         // entries staged in LDS (>= max expected n)
constexpr int FARCAP = 1 << 16;
constexpr int NCELL = 289;          // 17x17 cells; cell 289 = trash
constexpr float FARTH = 30.0f;

// Workspace layout (bytes):
//   [0, 32768)         int  cnt[NTILE]
//   [32768, 32772)     int  farcnt                      (pad to 32896)
//   [32896, +8*FARCAP) int2 farlist[FARCAP]
//   [WS_LIST, +2*NTILE*LCAP) u16 list
//   [WS_IMT,  +B*HW*C*4)     float imT[b][p][c]   (if ws_size permits)
constexpr size_t WS_CNT  = 0;
constexpr size_t WS_FCNT = 32768;
constexpr size_t WS_FLST = 32896;
constexpr size_t WS_LIST = WS_FLST + (size_t)FARCAP * 8;
constexpr size_t WS_IMT  = (WS_LIST + (size_t)NTILE * LCAP * 2 + 255) & ~(size_t)255;
constexpr size_t IMT_BYTES = (size_t)B * HW * C * 4;

// ---- pass 1: fused transpose + exact binning ----
// Block = 256 consecutive pixels of batch b. CL=true also emits imT.
template <bool CL>
__global__ __launch_bounds__(256) void fwarp_prep(
    const float* __restrict__ im0,
    const float* __restrict__ flow,
    float* __restrict__ imT,
    int* __restrict__ cnt,
    int* __restrict__ farcnt,
    int2* __restrict__ farlist,
    unsigned short* __restrict__ list) {

  __shared__ float t[256 * 17];               // +17 stride: conflict-free
  const int blk = blockIdx.x;                 // 8192 = B * (HW/256)
  const int b   = blk >> 10;
  const int p0  = (blk & 1023) * 256;
  const int tid = threadIdx.x;
  const int lane = tid & 63;
  const int p   = p0 + tid;
  const int idx = (b << 18) + p;

  // issue the 16 channel loads early; binning work overlaps their latency
  float v[16];
  if (CL) {
    const float* src = im0 + (size_t)b * C * HW + p0;
    #pragma unroll
    for (int c = 0; c < C; ++c) v[c] = src[(size_t)c * HW + tid];
  }

  float2 f = reinterpret_cast<const float2*>(flow)[idx];
  const int hh = p >> 9, ww = p & (W - 1);

  const bool isfar = (fabsf(f.x) > FARTH || fabsf(f.y) > FARTH);
  if (isfar) {
    unsigned long long m = __ballot(true);
    int ldr = __ffsll((long long)m) - 1;
    int base = 0;
    if (lane == ldr) base = atomicAdd(farcnt, (int)__popcll(m));
    base = __shfl(base, ldr);
    int s = base + (int)__popcll(m & ((1ull << lane) - 1));
    if (s < FARCAP) farlist[s] = make_int2(idx, -1);
  } else {
    float x = (float)ww + f.x;
    float y = (float)hh + f.y;
    int x0 = (int)floorf(x);
    int y0 = (int)floorf(y);

    int txA = ((unsigned)x0       < (unsigned)W) ? (x0 >> 4)       : -1;
    int txB = ((unsigned)(x0 + 1) < (unsigned)W) ? ((x0 + 1) >> 4) : -1;
    if (txB == txA) txB = -1;
    int tyA = ((unsigned)y0       < (unsigned)H) ? (y0 >> 4)       : -1;
    int tyB = ((unsigned)(y0 + 1) < (unsigned)H) ? ((y0 + 1) >> 4) : -1;
    if (tyB == tyA) tyB = -1;

    int clt[4];
    clt[0] = (tyA >= 0 && txA >= 0) ? ((b << 10) | (tyA << 5) | txA) : -1;
    clt[1] = (tyA >= 0 && txB >= 0) ? ((b << 10) | (tyA << 5) | txB) : -1;
    clt[2] = (tyB >= 0 && txA >= 0) ? ((b << 10) | (tyB << 5) | txA) : -1;
    clt[3] = (tyB >= 0 && txB >= 0) ? ((b << 10) | (tyB << 5) | txB) : -1;

    #pragma unroll
    for (int r = 0; r < 4; ++r) {
      int tt = clt[r];
      bool want = (tt >= 0);
      unsigned long long alive = __ballot(want);
      while (alive) {                         // uniform among active lanes
        int src = __ffsll((long long)alive) - 1;
        int t0  = __shfl(tt, src);
        unsigned long long grp = __ballot(want && tt == t0);
        int base = 0;
        if (lane == src) base = atomicAdd(&cnt[t0], (int)__popcll(grp));
        base = __shfl(base, src);
        if (want && tt == t0) {
          int slot = base + (int)__popcll(grp & ((1ull << lane) - 1));
          int tty = (t0 >> 5) & 31, ttx = t0 & 31;
          int cy = hh - (tty * T - R);        // in [1,78]
          int cx = ww - (ttx * T - R);
          if (slot < LCAP) {
            list[(size_t)t0 * LCAP + slot] = (unsigned short)((cy << 7) | cx);
          } else {
            int s2 = atomicAdd(farcnt, 1);    // never expected
            if (s2 < FARCAP) farlist[s2] = make_int2(idx, t0);
          }
          want = false;
        }
        alive &= ~grp;
      }
    }
  }

  if (CL) {
    #pragma unroll
    for (int c = 0; c < C; ++c) t[tid * 17 + c] = v[c];
    __syncthreads();
    float4* dst = reinterpret_cast<float4*>(imT + ((size_t)b * HW + p0) * C);
    #pragma unroll
    for (int i = 0; i < 4; ++i) {
      int k = i * 256 + tid;                  // 1024 float4 per block
      int pp = k >> 2, c4 = (k & 3) * 4;
      const float* tp = &t[pp * 17 + c4];
      dst[k] = make_float4(tp[0], tp[1], tp[2], tp[3]);  // coalesced
    }
  }
}

// ---- pass 2: destination-major gather, LDS-staged channels ----
template <bool CL>
__global__ __launch_bounds__(256, 4) void fwarp_gather(
    const float* __restrict__ im0,
    const float* __restrict__ imT,
    const float* __restrict__ flow,
    float* __restrict__ out,
    const int* __restrict__ cnt,
    const unsigned short* __restrict__ list) {

  __shared__ int            s_cnt[292];     // cell counts, then fill cursors
  __shared__ int            s_seg[32];
  __shared__ int            s_start[292];   // exclusive starts, cells 0..289
  __shared__ int            s_p[LCAP];
  __shared__ float2         s_f[LCAP];
  __shared__ unsigned short s_cellid[LCAP];
  __shared__ unsigned short s_ord[LCAP];
  __shared__ float          vch[VSTAGE * 16];  // 25.6 KB; total ~40.3 KB

  const int tcx = blockIdx.x, tcy = blockIdx.y, b = blockIdx.z;
  const int tx0 = tcx * T, ty0 = tcy * T;
  const int tid = threadIdx.x;
  const int tile = (b << 10) | (tcy << 5) | tcx;
  const int hy0 = ty0 - R, wx0 = tx0 - R;

  for (int i = tid; i < 292; i += 256) s_cnt[i] = 0;
  __syncthreads();

  const float2* __restrict__ flowv =
      reinterpret_cast<const float2*>(flow) + (size_t)b * HW;
  const int n = min(cnt[tile], LCAP);
  const unsigned short* lp = list + (size_t)tile * LCAP;

  // 2a: decode entries, compute cell + fractionals, count per cell
  for (int i = tid; i < n; i += 256) {
    int rc = lp[i];
    int hh = hy0 + (rc >> 7);
    int ww = wx0 + (rc & 127);
    int p  = (hh << 9) | ww;
    float2 f = flowv[p];
    float x = (float)ww + f.x, y = (float)hh + f.y;
    float x0f = floorf(x), y0f = floorf(y);
    int cx = (int)x0f - tx0 + 1;
    int cy = (int)y0f - ty0 + 1;
    int cell = ((unsigned)cx <= 16u && (unsigned)cy <= 16u) ? cy * 17 + cx
                                                            : NCELL;  // trash
    s_p[i] = p;
    s_f[i] = make_float2(x - x0f, y - y0f);
    s_cellid[i] = (unsigned short)cell;
    atomicAdd(&s_cnt[cell], 1);
  }
  __syncthreads();

  // exclusive prefix sum over 290 counts (29 segments x 10)
  if (tid < 29) {
    int sum = 0;
    #pragma unroll
    for (int j = 0; j < 10; ++j) {
      int ix = tid * 10 + j;
      s_start[ix] = sum;
      sum += s_cnt[ix];
    }
    s_seg[tid] = sum;
  }
  __syncthreads();
  if (tid == 0) {
    int run = 0;
    for (int t2 = 0; t2 < 29; ++t2) { int vv = s_seg[t2]; s_seg[t2] = run; run += vv; }
  }
  __syncthreads();
  for (int i = tid; i < 290; i += 256) s_start[i] += s_seg[i / 10];
  for (int i = tid; i < 292; i += 256) s_cnt[i] = 0;   // -> fill cursors
  __syncthreads();

  // 2b: scatter entry ids into CSR order
  for (int i = tid; i < n; i += 256) {
    int cell = s_cellid[i];
    int pos = s_start[cell] + atomicAdd(&s_cnt[cell], 1);
    s_ord[pos] = (unsigned short)i;
  }

  // 2b': stage each entry's 16 channels ONCE into LDS (coalesced).
  const int nstage = min(n, VSTAGE);
  if (CL) {
    for (int k = tid; k < nstage * 4; k += 256) {
      int i = k >> 2, q = k & 3;               // 4 lanes share one 64B line
      const float4* s4 = reinterpret_cast<const float4*>(imT) +
                         ((size_t)b * HW + s_p[i]) * 4 + q;
      reinterpret_cast<float4*>(vch)[i * 4 + q] = *s4;
    }
  } else {
    for (int k = tid; k < nstage * 16; k += 256) {
      int i = k >> 4, c = k & 15;
      vch[i * 16 + c] = im0[(size_t)b * C * HW + (size_t)c * HW + s_p[i]];
    }
  }
  __syncthreads();

  // 2c: one thread per output pixel, 16-channel register accumulation
  float a[16];
  #pragma unroll
  for (int c = 0; c < 16; ++c) a[c] = 0.0f;
  const int lx = tid & 15, ly = tid >> 4;

  #pragma unroll
  for (int k = 0; k < 4; ++k) {
    int cell = (ly + 1 - (k >> 1)) * 17 + (lx + 1 - (k & 1));
    int s = s_start[cell], e = s_start[cell + 1];
    for (int j = s; j < e; ++j) {
      int id = s_ord[j];
      float2 f = s_f[id];
      float wgt = ((k & 1) ? f.x : 1.0f - f.x) * ((k >> 1) ? f.y : 1.0f - f.y);
      if (id < VSTAGE) {
        const float4* vp = reinterpret_cast<const float4*>(vch) + id * 4;
        float4 q0 = vp[0], q1 = vp[1], q2 = vp[2], q3 = vp[3];
        a[0]  += wgt * q0.x; a[1]  += wgt * q0.y;
        a[2]  += wgt * q0.z; a[3]  += wgt * q0.w;
        a[4]  += wgt * q1.x; a[5]  += wgt * q1.y;
        a[6]  += wgt * q1.z; a[7]  += wgt * q1.w;
        a[8]  += wgt * q2.x; a[9]  += wgt * q2.y;
        a[10] += wgt * q2.z; a[11] += wgt * q2.w;
        a[12] += wgt * q3.x; a[13] += wgt * q3.y;
        a[14] += wgt * q3.z; a[15] += wgt * q3.w;
      } else if (CL) {                       // rare spill past VSTAGE
        const float4* v4 = reinterpret_cast<const float4*>(imT) +
                           ((size_t)b * HW + s_p[id]) * 4;
        float4 q0 = v4[0], q1 = v4[1], q2 = v4[2], q3 = v4[3];
        a[0]  += wgt * q0.x; a[1]  += wgt * q0.y;
        a[2]  += wgt * q0.z; a[3]  += wgt * q0.w;
        a[4]  += wgt * q1.x; a[5]  += wgt * q1.y;
        a[6]  += wgt * q1.z; a[7]  += wgt * q1.w;
        a[8]  += wgt * q2.x; a[9]  += wgt * q2.y;
        a[10] += wgt * q2.z; a[11] += wgt * q2.w;
        a[12] += wgt * q3.x; a[13] += wgt * q3.y;
        a[14] += wgt * q3.z; a[15] += wgt * q3.w;
      } else {
        const float* sp = im0 + (size_t)b * C * HW + s_p[id];
        #pragma unroll
        for (int c = 0; c < 16; ++c) a[c] += wgt * sp[(size_t)c * HW];
      }
    }
  }

  // direct register->global writeout (exclusive ownership, coalesced per c)
  float* ob = out + (size_t)b * C * HW + (size_t)(ty0 + ly) * W + (tx0 + lx);
  #pragma unroll
  for (int c = 0; c < 16; ++c) ob[(size_t)c * HW] = a[c];
}

// ---- pass 3: far pixels + overflow entries, global-atomic splat ----
__global__ __launch_bounds__(256) void fwarp_far(
    const float* __restrict__ im0,
    const float* __restrict__ flow,
    float* __restrict__ out,
    const int* __restrict__ farcnt,
    const int2* __restrict__ farlist) {

  int nf = min(*farcnt, FARCAP);
  for (int i = blockIdx.x * 256 + threadIdx.x; i < nf; i += gridDim.x * 256) {
    int2 ent = farlist[i];
    int idx  = ent.x;
    int tile = ent.y;
    int b  = idx >> 18;
    int p  = idx & (HW - 1);
    int hh = p >> 9, ww = p & (W - 1);
    float2 f = reinterpret_cast<const float2*>(flow)[idx];
    float x = (float)ww + f.x;
    float y = (float)hh + f.y;
    float x0f = floorf(x), y0f = floorf(y);
    int x0 = (int)x0f, y0 = (int)y0f;
    float fx = x - x0f, fy = y - y0f;
    float w00 = (1.0f - fx) * (1.0f - fy), w01 = fx * (1.0f - fy);
    float w10 = (1.0f - fx) * fy,          w11 = fx * fy;

    bool vx0 = (unsigned)x0       < (unsigned)W;
    bool vx1 = (unsigned)(x0 + 1) < (unsigned)W;
    bool vy0 = (unsigned)y0       < (unsigned)H;
    bool vy1 = (unsigned)(y0 + 1) < (unsigned)H;
    if (tile >= 0) {
      // overflow entry: apply ONLY corners landing in this tile's pixels
      int ttx = tile & 31, tty = (tile >> 5) & 31;
      int lx = x0 - ttx * T, ly = y0 - tty * T;
      vx0 &= (unsigned)lx       < (unsigned)T;
      vx1 &= (unsigned)(lx + 1) < (unsigned)T;
      vy0 &= (unsigned)ly       < (unsigned)T;
      vy1 &= (unsigned)(ly + 1) < (unsigned)T;
    }
    bool p00 = vx0 && vy0, p01 = vx1 && vy0, p10 = vx0 && vy1, p11 = vx1 && vy1;
    if (!(p00 | p01 | p10 | p11)) continue;

    int g00 = y0 * W + x0;
    const float* src = im0 + (size_t)b * C * HW + p;
    float* dst = out + (size_t)b * C * HW;
    for (int c = 0; c < C; ++c) {
      float v = src[(size_t)c * HW];
      float* o = dst + (size_t)c * HW;
      if (p00) atomicAdd(o + g00,         v * w00);
      if (p01) atomicAdd(o + g00 + 1,     v * w01);
      if (p10) atomicAdd(o + g00 + W,     v * w10);
      if (p11) atomicAdd(o + g00 + W + 1, v * w11);
    }
  }
}

extern "C" void kernel_launch(void* const* d_in, const int* in_sizes, int n_in,
                              void* d_out, int out_size, void* d_ws, size_t ws_size,
                              hipStream_t stream) {
  const float* im0  = (const float*)d_in[0];
  const float* flow = (const float*)d_in[1];
  float* out = (float*)d_out;

  char* wsb = (char*)d_ws;
  int*            cnt     = (int*)(wsb + WS_CNT);
  int*            farcnt  = (int*)(wsb + WS_FCNT);
  int2*           farlist = (int2*)(wsb + WS_FLST);
  unsigned short* list    = (unsigned short*)(wsb + WS_LIST);
  float*          imT     = (float*)(wsb + WS_IMT);

  const bool useT = ws_size >= WS_IMT + IMT_BYTES;

  hipMemsetAsync(wsb, 0, WS_FLST, stream);   // cnt + farcnt

  if (useT)
    fwarp_prep<true><<<8192, 256, 0, stream>>>(im0, flow, imT, cnt, farcnt,
                                               farlist, list);
  else
    fwarp_prep<false><<<8192, 256, 0, stream>>>(im0, flow, imT, cnt, farcnt,
                                                farlist, list);

  dim3 grid(TX, TY, B);
  if (useT)
    fwarp_gather<true><<<grid, 256, 0, stream>>>(im0, imT, flow, out, cnt, list);
  else
    fwarp_gather<false><<<grid, 256, 0, stream>>>(im0, imT, flow, out, cnt, list);

  fwarp_far<<<64, 256, 0, stream>>>(im0, flow, out, farcnt, farlist);
}

// Round 4
// 385.832 us; speedup vs baseline: 2.9336x; 1.2204x over previous
//
#include <hip/hip_runtime.h>

// Forward warp (bilinear splat), v6.
//
// R3 post-mortem: prep (fused transpose+bin) = 155us, latency-bound (VALU 17%,
// HBM 20%, occ 82%): the ballot-aggregation while-loop serializes ~25-40
// dependent device-atomic rounds per wave (atomicAdd->shfl chain ~600-900cy
// each on cnt[]'s LLC lines). v6:
//  - prep: block-local LDS histogram over the 5x21 reachable tile window.
//    Phase A: LDS atomicAdd per claim (returns local slot). Phase B: <=105
//    PARALLEL global atomics (one per nonzero local tile, single round).
//    Phase C: write entries at base+slot. No serial atomic chain.
//  - list entries u64 {rel14, dx0:6, dy0:6, fx16, fy16}: gather no longer
//    re-gathers flow or does floor math; pure decode.
//  - gather: codes scattered directly into CSR order (no s_ord/s_p/s_f),
//    LDS 40.3 -> 31.2 KB => 5 blocks/CU (was 3).

constexpr int B = 8;
constexpr int C = 16;
constexpr int H = 512;
constexpr int W = 512;
constexpr int HW = H * W;

constexpr int T    = 16;            // output tile side
constexpr int R    = 32;            // halo radius (covers |flow| <= 30)
constexpr int TX   = W / T;         // 32
constexpr int TY   = H / T;         // 32
constexpr int NTILE = B * TX * TY;  // 8192
constexpr int LCAP = 400;           // per-tile cap == LDS stage capacity (exp ~290, max ~380)
constexpr int FARCAP = 1 << 16;
constexpr int NCELL = 289;          // 17x17 cells; 289 = trash
constexpr float FARTH = 30.0f;

// prep local tile window: block = 256 px of one row -> claims within 5 rows x 21 cols
constexpr int LW = 21;
constexpr int LH = 5;
constexpr int NLT = LW * LH;        // 105
constexpr int FARSLOT = NLT;        // lcnt[105] counts far pixels

// Workspace layout (bytes):
//   [0, 32768)         int  cnt[NTILE]
//   [32768, 32772)     int  farcnt                      (pad to 32896)
//   [32896, +8*FARCAP) int2 farlist[FARCAP]
//   [WS_LIST, +8*NTILE*LCAP) u64 list                   (26.2 MB)
//   [WS_IMT,  +B*HW*C*4)     float imT[b][p][c]         (if ws_size permits)
constexpr size_t WS_CNT  = 0;
constexpr size_t WS_FCNT = 32768;
constexpr size_t WS_FLST = 32896;
constexpr size_t WS_LIST = WS_FLST + (size_t)FARCAP * 8;           // 557184 (8-aligned)
constexpr size_t WS_IMT  = (WS_LIST + (size_t)NTILE * LCAP * 8 + 255) & ~(size_t)255;
constexpr size_t IMT_BYTES = (size_t)B * HW * C * 4;

// ---- pass 1: fused transpose + histogram binning ----
template <bool CL>
__global__ __launch_bounds__(256) void fwarp_prep(
    const float* __restrict__ im0,
    const float* __restrict__ flow,
    float* __restrict__ imT,
    int* __restrict__ cnt,
    int* __restrict__ farcnt,
    int2* __restrict__ farlist,
    unsigned long long* __restrict__ list) {

  __shared__ float t[256 * 17];        // transpose staging (+17: conflict-free)
  __shared__ int   lcnt[NLT + 1];      // local histogram + far count
  __shared__ int   lbase[NLT + 1];     // reserved global bases

  const int blk = blockIdx.x;          // 8192 = B * (HW/256)
  const int b   = blk >> 10;
  const int p0  = (blk & 1023) * 256;
  const int tid = threadIdx.x;
  const int p   = p0 + tid;            // exact: no bounds check needed
  const int idx = (b << 18) + p;
  const int hh  = p >> 9, ww = p & (W - 1);

  for (int i = tid; i < NLT + 1; i += 256) lcnt[i] = 0;

  // issue the 16 channel loads early; binning overlaps their latency
  float v[16];
  if (CL) {
    const float* src = im0 + (size_t)b * C * HW + p0;
    #pragma unroll
    for (int c = 0; c < C; ++c) v[c] = src[(size_t)c * HW + tid];
  }

  float2 f = reinterpret_cast<const float2*>(flow)[idx];
  __syncthreads();                     // lcnt zeroed

  const int tyb = (hh - 31) >> 4;      // arithmetic shift: floor for negatives
  const int txb = ((p0 & (W - 1)) - 31) >> 4;

  const bool isfar = (fabsf(f.x) > FARTH || fabsf(f.y) > FARTH);

  int lts[4], tiles[4], rels[4], slots[4];
  unsigned ehi = 0, elo = 0;

  if (!isfar) {
    float x = (float)ww + f.x;
    float y = (float)hh + f.y;
    float x0f = floorf(x), y0f = floorf(y);
    int x0 = (int)x0f, y0 = (int)y0f;
    float fx = x - x0f, fy = y - y0f;
    unsigned fx16 = min((unsigned)(fx * 65536.0f), 65535u);
    unsigned fy16 = min((unsigned)(fy * 65536.0f), 65535u);
    ehi = fx16 | (fy16 << 16);
    int dxe = x0 - ww + 32;            // in [2,62]
    int dye = y0 - hh + 32;
    elo = ((unsigned)dxe << 14) | ((unsigned)dye << 20);

    int txA = ((unsigned)x0       < (unsigned)W) ? (x0 >> 4)       : -1;
    int txB = ((unsigned)(x0 + 1) < (unsigned)W) ? ((x0 + 1) >> 4) : -1;
    if (txB == txA) txB = -1;
    int tyA = ((unsigned)y0       < (unsigned)H) ? (y0 >> 4)       : -1;
    int tyB = ((unsigned)(y0 + 1) < (unsigned)H) ? ((y0 + 1) >> 4) : -1;
    if (tyB == tyA) tyB = -1;

    #pragma unroll
    for (int k = 0; k < 4; ++k) {      // fully unrolled: static indexing
      int ty = (k >> 1) ? tyB : tyA;
      int tx = (k & 1)  ? txB : txA;
      bool ok = (ty >= 0) && (tx >= 0);
      lts[k]   = ok ? (ty - tyb) * LW + (tx - txb) : -1;
      tiles[k] = (b << 10) | (ty << 5) | tx;
      rels[k]  = ((hh - (ty * T - R)) << 7) | (ww - (tx * T - R));
    }
  } else {
    #pragma unroll
    for (int k = 0; k < 4; ++k) lts[k] = -1;
  }

  // phase A: local histogram (LDS atomics return local slot)
  int sfar = -1;
  if (isfar) sfar = atomicAdd(&lcnt[FARSLOT], 1);
  #pragma unroll
  for (int k = 0; k < 4; ++k)
    if (lts[k] >= 0) slots[k] = atomicAdd(&lcnt[lts[k]], 1);
  __syncthreads();

  // phase B: ONE parallel round of global reservations
  if (tid < NLT + 1) {
    int g = lcnt[tid];
    if (g > 0) {
      if (tid == FARSLOT) {
        lbase[tid] = atomicAdd(farcnt, g);
      } else {
        int ty = tyb + tid / LW;
        int tx = txb + tid % LW;
        int tile = (b << 10) | (ty << 5) | tx;
        lbase[tid] = atomicAdd(&cnt[tile], g);
      }
    }
  }
  __syncthreads();

  // phase C: write entries at base + local slot
  if (isfar) {
    int s = lbase[FARSLOT] + sfar;
    if (s < FARCAP) farlist[s] = make_int2(idx, -1);
  } else {
    #pragma unroll
    for (int k = 0; k < 4; ++k) {
      if (lts[k] >= 0) {
        int slot = lbase[lts[k]] + slots[k];
        if (slot < LCAP) {
          list[(size_t)tiles[k] * LCAP + slot] =
              ((unsigned long long)ehi << 32) | elo | (unsigned)rels[k];
        } else {                        // overflow (never expected)
          int s2 = atomicAdd(farcnt, 1);
          if (s2 < FARCAP) farlist[s2] = make_int2(idx, tiles[k]);
        }
      }
    }
  }

  // transpose writeout
  if (CL) {
    #pragma unroll
    for (int c = 0; c < C; ++c) t[tid * 17 + c] = v[c];
    __syncthreads();
    float4* dst = reinterpret_cast<float4*>(imT + ((size_t)b * HW + p0) * C);
    #pragma unroll
    for (int i = 0; i < 4; ++i) {
      int k = i * 256 + tid;
      int pp = k >> 2, c4 = (k & 3) * 4;
      const float* tp = &t[pp * 17 + c4];
      dst[k] = make_float4(tp[0], tp[1], tp[2], tp[3]);
    }
  }
}

// ---- pass 2: destination-major gather, CSR-ordered codes, LDS-staged channels ----
template <bool CL>
__global__ __launch_bounds__(256, 5) void fwarp_gather(
    const float* __restrict__ im0,
    const float* __restrict__ imT,
    float* __restrict__ out,
    const int* __restrict__ cnt,
    const unsigned long long* __restrict__ list) {

  __shared__ int      s_cnt[290];      // cell counts, then fill cursors
  __shared__ int      s_start[290];    // exclusive starts, cells 0..289
  __shared__ int      s_seg[29];
  __shared__ unsigned s_code[LCAP];    // rel|dxe|dye  (CSR order)
  __shared__ unsigned s_fq[LCAP];      // fx16|fy16    (CSR order)
  __shared__ float    vch[LCAP * 16];  // 25.6 KB; total ~31.2 KB -> 5 blocks/CU

  const int tcx = blockIdx.x, tcy = blockIdx.y, b = blockIdx.z;
  const int tx0 = tcx * T, ty0 = tcy * T;
  const int tid = threadIdx.x;
  const int tile = (b << 10) | (tcy << 5) | tcx;
  const int hy0 = ty0 - R, wx0 = tx0 - R;

  for (int i = tid; i < 290; i += 256) s_cnt[i] = 0;
  __syncthreads();

  const int n = min(cnt[tile], LCAP);
  const unsigned long long* lp = list + (size_t)tile * LCAP;

  // 2a: read entries (<=2/thread), decode cell, count per cell
  unsigned lo[2], hi[2];
  int cell[2];
  #pragma unroll
  for (int r = 0; r < 2; ++r) {
    int i = tid + r * 256;
    cell[r] = -1;
    if (i < n) {
      unsigned long long e = lp[i];
      lo[r] = (unsigned)e;
      hi[r] = (unsigned)(e >> 32);
      int rel = lo[r] & 0x3fff;
      int dxe = (lo[r] >> 14) & 63;
      int dye = (lo[r] >> 20) & 63;
      int cx = (rel & 127) + dxe - 63;   // x0 - tx0 + 1
      int cy = (rel >> 7)  + dye - 63;   // y0 - ty0 + 1
      cell[r] = ((unsigned)cx <= 16u && (unsigned)cy <= 16u) ? cy * 17 + cx
                                                             : NCELL;
      atomicAdd(&s_cnt[cell[r]], 1);
    }
  }
  __syncthreads();

  // exclusive prefix sum over 290 counts (29 segments x 10)
  if (tid < 29) {
    int sum = 0;
    #pragma unroll
    for (int j = 0; j < 10; ++j) {
      int ix = tid * 10 + j;
      s_start[ix] = sum;
      sum += s_cnt[ix];
    }
    s_seg[tid] = sum;
  }
  __syncthreads();
  if (tid == 0) {
    int run = 0;
    for (int t2 = 0; t2 < 29; ++t2) { int vv = s_seg[t2]; s_seg[t2] = run; run += vv; }
  }
  __syncthreads();
  for (int i = tid; i < 290; i += 256) s_start[i] += s_seg[i / 10];
  for (int i = tid; i < 290; i += 256) s_cnt[i] = 0;   // -> fill cursors
  __syncthreads();

  // 2b: scatter codes directly into CSR order
  #pragma unroll
  for (int r = 0; r < 2; ++r) {
    if (cell[r] >= 0) {
      int pos = s_start[cell[r]] + atomicAdd(&s_cnt[cell[r]], 1);
      s_code[pos] = lo[r];
      s_fq[pos]   = hi[r];
    }
  }
  __syncthreads();

  // 2b': stage each entry's 16 channels ONCE into LDS
  if (CL) {
    for (int k = tid; k < n * 4; k += 256) {
      int i = k >> 2, q = k & 3;                 // 4 lanes share one 64B line
      int rel = s_code[i] & 0x3fff;
      int p = ((hy0 + (rel >> 7)) << 9) | (wx0 + (rel & 127));
      const float4* s4 = reinterpret_cast<const float4*>(imT) +
                         ((size_t)b * HW + p) * 4 + q;
      reinterpret_cast<float4*>(vch)[i * 4 + q] = *s4;
    }
  } else {
    for (int k = tid; k < n * 16; k += 256) {
      int i = k >> 4, c = k & 15;
      int rel = s_code[i] & 0x3fff;
      int p = ((hy0 + (rel >> 7)) << 9) | (wx0 + (rel & 127));
      vch[i * 16 + c] = im0[(size_t)b * C * HW + (size_t)c * HW + p];
    }
  }
  __syncthreads();

  // 2c: one thread per output pixel, 16-channel register accumulation
  float a[16];
  #pragma unroll
  for (int c = 0; c < 16; ++c) a[c] = 0.0f;
  const int lx = tid & 15, ly = tid >> 4;

  #pragma unroll
  for (int k = 0; k < 4; ++k) {
    int cell2 = (ly + 1 - (k >> 1)) * 17 + (lx + 1 - (k & 1));
    int s = s_start[cell2];
    int e = (cell2 < 289) ? s_start[cell2 + 1] : n;
    for (int j = s; j < e; ++j) {
      unsigned fq = s_fq[j];
      float fx = (float)(fq & 0xffffu) * (1.0f / 65536.0f);
      float fy = (float)(fq >> 16)     * (1.0f / 65536.0f);
      float wgt = ((k & 1) ? fx : 1.0f - fx) * ((k >> 1) ? fy : 1.0f - fy);
      const float4* vp = reinterpret_cast<const float4*>(vch) + j * 4;
      float4 q0 = vp[0], q1 = vp[1], q2 = vp[2], q3 = vp[3];
      a[0]  += wgt * q0.x; a[1]  += wgt * q0.y;
      a[2]  += wgt * q0.z; a[3]  += wgt * q0.w;
      a[4]  += wgt * q1.x; a[5]  += wgt * q1.y;
      a[6]  += wgt * q1.z; a[7]  += wgt * q1.w;
      a[8]  += wgt * q2.x; a[9]  += wgt * q2.y;
      a[10] += wgt * q2.z; a[11] += wgt * q2.w;
      a[12] += wgt * q3.x; a[13] += wgt * q3.y;
      a[14] += wgt * q3.z; a[15] += wgt * q3.w;
    }
  }

  // direct register->global writeout (exclusive ownership, coalesced per c)
  float* ob = out + (size_t)b * C * HW + (size_t)(ty0 + ly) * W + (tx0 + lx);
  #pragma unroll
  for (int c = 0; c < 16; ++c) ob[(size_t)c * HW] = a[c];
}

// ---- pass 3: far pixels + overflow entries, global-atomic splat ----
__global__ __launch_bounds__(256) void fwarp_far(
    const float* __restrict__ im0,
    const float* __restrict__ flow,
    float* __restrict__ out,
    const int* __restrict__ farcnt,
    const int2* __restrict__ farlist) {

  int nf = min(*farcnt, FARCAP);
  for (int i = blockIdx.x * 256 + threadIdx.x; i < nf; i += gridDim.x * 256) {
    int2 ent = farlist[i];
    int idx  = ent.x;
    int tile = ent.y;
    int b  = idx >> 18;
    int p  = idx & (HW - 1);
    int hh = p >> 9, ww = p & (W - 1);
    float2 f = reinterpret_cast<const float2*>(flow)[idx];
    float x = (float)ww + f.x;
    float y = (float)hh + f.y;
    float x0f = floorf(x), y0f = floorf(y);
    int x0 = (int)x0f, y0 = (int)y0f;
    float fx = x - x0f, fy = y - y0f;
    float w00 = (1.0f - fx) * (1.0f - fy), w01 = fx * (1.0f - fy);
    float w10 = (1.0f - fx) * fy,          w11 = fx * fy;

    bool vx0 = (unsigned)x0       < (unsigned)W;
    bool vx1 = (unsigned)(x0 + 1) < (unsigned)W;
    bool vy0 = (unsigned)y0       < (unsigned)H;
    bool vy1 = (unsigned)(y0 + 1) < (unsigned)H;
    if (tile >= 0) {
      // overflow entry: apply ONLY corners landing in this tile's pixels
      int ttx = tile & 31, tty = (tile >> 5) & 31;
      int lx = x0 - ttx * T, ly = y0 - tty * T;
      vx0 &= (unsigned)lx       < (unsigned)T;
      vx1 &= (unsigned)(lx + 1) < (unsigned)T;
      vy0 &= (unsigned)ly       < (unsigned)T;
      vy1 &= (unsigned)(ly + 1) < (unsigned)T;
    }
    bool p00 = vx0 && vy0, p01 = vx1 && vy0, p10 = vx0 && vy1, p11 = vx1 && vy1;
    if (!(p00 | p01 | p10 | p11)) continue;

    int g00 = y0 * W + x0;
    const float* src = im0 + (size_t)b * C * HW + p;
    float* dst = out + (size_t)b * C * HW;
    for (int c = 0; c < C; ++c) {
      float v = src[(size_t)c * HW];
      float* o = dst + (size_t)c * HW;
      if (p00) atomicAdd(o + g00,         v * w00);
      if (p01) atomicAdd(o + g00 + 1,     v * w01);
      if (p10) atomicAdd(o + g00 + W,     v * w10);
      if (p11) atomicAdd(o + g00 + W + 1, v * w11);
    }
  }
}

extern "C" void kernel_launch(void* const* d_in, const int* in_sizes, int n_in,
                              void* d_out, int out_size, void* d_ws, size_t ws_size,
                              hipStream_t stream) {
  const float* im0  = (const float*)d_in[0];
  const float* flow = (const float*)d_in[1];
  float* out = (float*)d_out;

  char* wsb = (char*)d_ws;
  int*                cnt     = (int*)(wsb + WS_CNT);
  int*                farcnt  = (int*)(wsb + WS_FCNT);
  int2*               farlist = (int2*)(wsb + WS_FLST);
  unsigned long long* list    = (unsigned long long*)(wsb + WS_LIST);
  float*              imT     = (float*)(wsb + WS_IMT);

  const bool useT = ws_size >= WS_IMT + IMT_BYTES;

  hipMemsetAsync(wsb, 0, WS_FLST, stream);   // cnt + farcnt

  if (useT)
    fwarp_prep<true><<<8192, 256, 0, stream>>>(im0, flow, imT, cnt, farcnt,
                                               farlist, list);
  else
    fwarp_prep<false><<<8192, 256, 0, stream>>>(im0, flow, imT, cnt, farcnt,
                                                farlist, list);

  dim3 grid(TX, TY, B);
  if (useT)
    fwarp_gather<true><<<grid, 256, 0, stream>>>(im0, imT, out, cnt, list);
  else
    fwarp_gather<false><<<grid, 256, 0, stream>>>(im0, imT, out, cnt, list);

  fwarp_far<<<64, 256, 0, stream>>>(im0, flow, out, farcnt, farlist);
}